// Round 1
// baseline (290.891 us; speedup 1.0000x reference)
//
#include <hip/hip_runtime.h>
#include <stdint.h>

// ---------------------------------------------------------------------------
// PDG2Seq_GCN: B=16, N=1024, C=O=64, D=10, CHEB_K=2 (K=5 stacked terms)
// Round 7: (1) drop cvt_adj — hops stage fp32 adj via global_load_lds and
// convert to bf16 in-register at fragment-read time (identical RNE numerics,
// saves a full 201 MB sweep); (2) drop WT (40 MB) — final_kernel regenerates
// per-node weights on the fly: loop d, MFMA against shared bf16 wpTb[d]
// (L2-resident), scale partial by emb[n,d]; (3) X1/X2 intermediates bf16.
// Launches: prep, hop1, hop2, final (4 kernels).
// ---------------------------------------------------------------------------

typedef __attribute__((ext_vector_type(4))) float f32x4;
typedef __attribute__((ext_vector_type(2))) float f32x2;
typedef __attribute__((ext_vector_type(8))) short s16x8;
typedef __attribute__((ext_vector_type(8))) __bf16 bf16x8;

__device__ __forceinline__ unsigned short f2bf(float f) {
  union { float f; uint32_t u; } v; v.f = f;
  uint32_t r = v.u + 0x7FFFu + ((v.u >> 16) & 1u);   // RNE
  return (unsigned short)(r >> 16);
}
__device__ __forceinline__ uint32_t pack2(float a, float b) {
  return (uint32_t)f2bf(a) | ((uint32_t)f2bf(b) << 16);
}

union FragU { s16x8 s; bf16x8 b; uint32_t u[4]; };

__device__ __forceinline__ void async_cp16(const void* g, void* l) {
  __builtin_amdgcn_global_load_lds(
      (const __attribute__((address_space(1))) void*)g,
      (__attribute__((address_space(3))) void*)l, 16, 0, 0);
}

// ---------------------------------------------------------------------------
// K1 prep: blocks 0..255 transpose x -> XT0 bf16 [b][c][n];
//          blocks 256..305 transpose wp -> wpTb bf16 [d][o][ki] (ki = k*64+c).
// ---------------------------------------------------------------------------
__global__ __launch_bounds__(256) void prep(const float* __restrict__ x,
                                            const float* __restrict__ wp,
                                            unsigned short* __restrict__ XT0,
                                            unsigned short* __restrict__ wpTb) {
  __shared__ __align__(16) char smem[17160];
  const int tid = threadIdx.x;
  const int bid = blockIdx.x;
  if (bid < 256) {
    unsigned short (*tl)[72] = (unsigned short(*)[72])smem;
    const int b = bid >> 4, n0 = (bid & 15) * 64;
    {
      const int c4 = (tid & 15) * 4;
#pragma unroll
      for (int i = 0; i < 4; ++i) {
        const int row = (tid >> 4) + i * 16;
        f32x4 v =
            *(const f32x4*)(x + ((size_t)(b * 1024 + n0 + row)) * 64 + c4);
        *(uint32_t*)&tl[row][c4]     = pack2(v[0], v[1]);
        *(uint32_t*)&tl[row][c4 + 2] = pack2(v[2], v[3]);
      }
    }
    __syncthreads();
    {
      const int c = tid >> 2;
      const int nch = (tid & 3) * 16;
      s16x8 s0, s1;
#pragma unroll
      for (int j = 0; j < 8; ++j) {
        s0[j] = (short)tl[nch + j][c];
        s1[j] = (short)tl[nch + 8 + j][c];
      }
      unsigned short* p = XT0 + (size_t)(b * 64 + c) * 1024 + n0 + nch;
      *(s16x8*)p = s0;
      *(s16x8*)(p + 8) = s1;
    }
  } else {
    float (*tl)[65] = (float(*)[65])smem;
    const int jj = bid - 256;
    const int d = jj / 5, ki0 = (jj % 5) * 64;
    const float* src = wp + (size_t)d * 20480;
    {
      const int o4 = (tid & 15) * 4;
#pragma unroll
      for (int i = 0; i < 4; ++i) {
        const int row = (tid >> 4) + i * 16;
        f32x4 v = *(const f32x4*)(src + (size_t)(ki0 + row) * 64 + o4);
        tl[row][o4] = v[0]; tl[row][o4 + 1] = v[1];
        tl[row][o4 + 2] = v[2]; tl[row][o4 + 3] = v[3];
      }
    }
    __syncthreads();
    {
      const int o = tid >> 2;
      const int kch = (tid & 3) * 16;
      unsigned short* dst =
          wpTb + (size_t)d * 20480 + (size_t)o * 320 + ki0 + kch;
      s16x8 s0, s1;
#pragma unroll
      for (int j = 0; j < 8; ++j) {
        s0[j] = (short)f2bf(tl[kch + j][o]);
        s1[j] = (short)f2bf(tl[kch + 8 + j][o]);
      }
      *(s16x8*)dst = s0;
      *(s16x8*)(dst + 8) = s1;
    }
  }
}

// ---------------------------------------------------------------------------
// hop body: out[64 rows][64] = A[1024x1024]fp32 @ X[1024x64]bf16, MFMA bf16.
// A staged fp32 (16 KB/stage, 4 DMA/wave), B staged bf16 (8 KB/stage, 2 DMA),
// double-buffered (48 KB LDS), 1 barrier/stage. Chunk-XOR swizzle on the
// GLOBAL source (rule: linear LDS dest + inverse-swizzled source + swizzled
// read). A-frag: 2x ds_read_b128 fp32 -> in-register RNE -> bf16x8.
// ---------------------------------------------------------------------------
__device__ __forceinline__ void hop_body(
    char* smem, const float* __restrict__ A,
    const unsigned short* __restrict__ XT, unsigned short* __restrict__ Xoutb,
    unsigned short* __restrict__ XTout, int write_xt, int rowbase) {
  const int tid = threadIdx.x;
  const int wave = tid >> 6, lane = tid & 63;
  const int l15 = lane & 15, q = lane >> 4;

  float* const Ast = (float*)smem;                              // [2][64][64] f32
  unsigned short* const Bst = (unsigned short*)(smem + 32768);  // [2][64][64] bf16

  // A staging: 4 instrs x 4 rows; lane: row_in4 = lane>>4, 16B chunk = lane&15
  const float* asrc[4];
  int aldso[4];
#pragma unroll
  for (int i = 0; i < 4; ++i) {
    const int r = wave * 16 + i * 4 + (lane >> 4);
    const int gch = (lane & 15) ^ (r & 7);     // pre-swizzled global chunk
    asrc[i] = A + (size_t)(rowbase + r) * 1024 + gch * 4;
    aldso[i] = (wave * 16 + i * 4) * 64;
  }
  // B staging: 2 instrs x 8 rows; lane: row_in8 = lane>>3, 16B chunk = lane&7
  const unsigned short* bsrc[2];
  int bldso[2];
#pragma unroll
  for (int i = 0; i < 2; ++i) {
    const int r = wave * 16 + i * 8 + (lane >> 3);
    bsrc[i] = XT + (size_t)r * 1024 + ((lane & 7) ^ (r & 7)) * 8;
    bldso[i] = (wave * 16 + i * 8) * 64;
  }

  f32x4 acc[4];
#pragma unroll
  for (int t = 0; t < 4; ++t) acc[t] = (f32x4){0.f, 0.f, 0.f, 0.f};

  auto issue = [&](int s, int k0) {
#pragma unroll
    for (int i = 0; i < 4; ++i)
      async_cp16(asrc[i] + k0, Ast + s * 4096 + aldso[i]);
#pragma unroll
    for (int i = 0; i < 2; ++i)
      async_cp16(bsrc[i] + k0, Bst + s * 4096 + bldso[i]);
  };
  const int sw = l15 & 7;
  auto compute = [&](int s) {
    const float* Ab = Ast + s * 4096 + (wave * 16 + l15) * 64;
    const unsigned short* Bb = Bst + s * 4096 + l15 * 64;
#pragma unroll
    for (int h = 0; h < 2; ++h) {
      // A-frag floats [h*32 + q*8 .. +8) = fp32 chunks g0, g0+1 (swizzled)
      const int g0 = h * 8 + q * 2;
      f32x4 lo = *(const f32x4*)(Ab + (g0 ^ sw) * 4);
      f32x4 hi = *(const f32x4*)(Ab + ((g0 + 1) ^ sw) * 4);
      FragU af;
      af.u[0] = pack2(lo[0], lo[1]);
      af.u[1] = pack2(lo[2], lo[3]);
      af.u[2] = pack2(hi[0], hi[1]);
      af.u[3] = pack2(hi[2], hi[3]);
      const int cko = ((h * 4 + q) ^ sw) * 8;
#pragma unroll
      for (int t = 0; t < 4; ++t) {
        FragU bf;
        bf.s = *(const s16x8*)(Bb + t * 1024 + cko);
        acc[t] = __builtin_amdgcn_mfma_f32_16x16x32_bf16(af.b, bf.b, acc[t],
                                                         0, 0, 0);
      }
    }
  };

  issue(0, 0);
#pragma unroll 1
  for (int kt = 0; kt < 16; ++kt) {
    const int cur = kt & 1;
    __syncthreads();                   // stage kt landed (vmcnt drain)
    if (kt + 1 < 16) issue(cur ^ 1, (kt + 1) * 64);
    compute(cur);
  }

  // Epilogue: transpose via LDS (reuse stage memory)
  __syncthreads();
  float (*tile)[65] = (float(*)[65])smem;
#pragma unroll
  for (int t = 0; t < 4; ++t)
#pragma unroll
    for (int rr = 0; rr < 4; ++rr)
      tile[wave * 16 + q * 4 + rr][t * 16 + l15] = acc[t][rr];
  __syncthreads();

  {  // node-major bf16 [n][c] for final_kernel
    const int row = tid >> 2;
    const int cb = (tid & 3) * 16;
    unsigned short* __restrict__ outp =
        Xoutb + (size_t)(rowbase + row) * 64 + cb;
    s16x8 s0, s1;
#pragma unroll
    for (int j = 0; j < 8; ++j) {
      s0[j] = (short)f2bf(tile[row][cb + j]);
      s1[j] = (short)f2bf(tile[row][cb + 8 + j]);
    }
    *(s16x8*)outp = s0;
    *(s16x8*)(outp + 8) = s1;
  }
  if (write_xt) {  // c-major bf16 [c][n] for next hop
    const int c = tid >> 2;
    const int nch = (tid & 3) * 16;
    unsigned short* __restrict__ xtp = XTout + (size_t)c * 1024 + rowbase + nch;
    s16x8 s0, s1;
#pragma unroll
    for (int j = 0; j < 8; ++j) {
      s0[j] = (short)f2bf(tile[nch + j][c]);
      s1[j] = (short)f2bf(tile[nch + 8 + j][c]);
    }
    *(s16x8*)xtp = s0;
    *(s16x8*)(xtp + 8) = s1;
  }
}

// ---------------------------------------------------------------------------
// K2 hop1: reads fp32 adj (HBM-cold), writes X1b bf16 + XT1 bf16.
// ---------------------------------------------------------------------------
__global__ __launch_bounds__(256, 3) void hop1_kernel(
    const float* __restrict__ adj, const unsigned short* __restrict__ XT0,
    unsigned short* __restrict__ X1b, unsigned short* __restrict__ XT1) {
  __shared__ __align__(16) char smem[49152];
  const int bx = blockIdx.x, slice = blockIdx.y, b = slice & 15;
  hop_body(smem, adj + (size_t)slice * 1048576, XT0 + (size_t)b * 65536,
           X1b + (size_t)slice * 65536, XT1 + (size_t)slice * 65536, 1,
           bx * 64);
}

// ---------------------------------------------------------------------------
// K3 hop2: reads fp32 adj (LLC-warm), reversed block order (hot tail first).
// ---------------------------------------------------------------------------
__global__ __launch_bounds__(256, 3) void hop2_kernel(
    const float* __restrict__ adj, const unsigned short* __restrict__ XT1,
    unsigned short* __restrict__ X2b) {
  __shared__ __align__(16) char smem[49152];
  const int bx = 15 - (int)blockIdx.x;
  const int slice = 31 - (int)blockIdx.y;
  hop_body(smem, adj + (size_t)slice * 1048576, XT1 + (size_t)slice * 65536,
           X2b + (size_t)slice * 65536, (unsigned short*)0, 0, bx * 64);
}

// ---------------------------------------------------------------------------
// K4 final: out[b,n,o] = sum_d emb[n,d] * (xg[b,n,:320] @ WpT_d[320,64])
//           + sum_d emb[n,d] * bp[d,o]
// Weights regenerated on the fly from L2-resident wpTb (410 KB) — no WT.
// 2 nodes/block, 2 waves per node (o halves). grid 512, block 256.
// ---------------------------------------------------------------------------
__global__ __launch_bounds__(256, 2) void final_kernel(
    const float* __restrict__ x, const unsigned short* __restrict__ X1b,
    const unsigned short* __restrict__ X2b,
    const unsigned short* __restrict__ wpTb, const float* __restrict__ emb,
    const float* __restrict__ bias_pool, float* __restrict__ out) {
  __shared__ unsigned short xg[2][16][328];
  const int tid = threadIdx.x;
  const int node_base = blockIdx.x * 2;

  for (int u = tid; u < 5120; u += 256) {       // units of 2 ki
    const int nd = u / 2560;
    int rem = u - nd * 2560;
    const int bb = rem / 160;
    const int kiu = rem - bb * 160;
    const int ki = kiu * 2;
    const int k = ki >> 6;
    const int c = ki & 63;
    const int nn = node_base + nd;
    uint32_t w;
    if (k == 0) {
      f32x2 v = *(const f32x2*)(x + ((size_t)bb * 1024 + nn) * 64 + c);
      w = pack2(v[0], v[1]);
    } else {
      const unsigned short* arr = (k == 1 || k == 3) ? X1b : X2b;
      const int s = (k >= 3) ? 1 : 0;
      w = *(const uint32_t*)(arr + ((size_t)(s * 16 + bb) * 1024 + nn) * 64 + c);
    }
    *(uint32_t*)&xg[nd][bb][ki] = w;
  }
  __syncthreads();

  const int wave = tid >> 6, lane = tid & 63;
  const int nd = wave >> 1, oh = wave & 1;
  const int l15 = lane & 15, q = lane >> 4;
  const int n = node_base + nd;

  // Hoist A-frags (xg rows, bf16) for the whole d-loop: 40 VGPRs.
  FragU af[10];
#pragma unroll
  for (int ks = 0; ks < 10; ++ks)
    af[ks].s = *(const s16x8*)&xg[nd][l15][ks * 32 + q * 8];

  f32x4 acc[2];
  acc[0] = (f32x4){0.f, 0.f, 0.f, 0.f};
  acc[1] = (f32x4){0.f, 0.f, 0.f, 0.f};

  // o = (oh*2+tt)*16 + l15 ; wpTb layout [d][o][ki]
  const unsigned short* wb0 = wpTb + (size_t)(oh * 32 + l15) * 320 + q * 8;
#pragma unroll 1
  for (int d = 0; d < 10; ++d) {
    const unsigned short* wd = wb0 + (size_t)d * 20480;
    f32x4 tmp[2];
    tmp[0] = (f32x4){0.f, 0.f, 0.f, 0.f};
    tmp[1] = (f32x4){0.f, 0.f, 0.f, 0.f};
#pragma unroll
    for (int ks = 0; ks < 10; ++ks) {
#pragma unroll
      for (int tt = 0; tt < 2; ++tt) {
        FragU bf;
        bf.s = *(const s16x8*)(wd + tt * 5120 + ks * 32);
        tmp[tt] = __builtin_amdgcn_mfma_f32_16x16x32_bf16(af[ks].b, bf.b,
                                                          tmp[tt], 0, 0, 0);
      }
    }
    const float e = emb[n * 10 + d];
#pragma unroll
    for (int tt = 0; tt < 2; ++tt)
#pragma unroll
      for (int rr = 0; rr < 4; ++rr)
        acc[tt][rr] += e * tmp[tt][rr];
  }

#pragma unroll
  for (int tt = 0; tt < 2; ++tt) {
    const int o = (oh * 2 + tt) * 16 + l15;
    float bv = 0.f;
#pragma unroll
    for (int d = 0; d < 10; ++d)
      bv += emb[n * 10 + d] * bias_pool[d * 64 + o];
#pragma unroll
    for (int rr = 0; rr < 4; ++rr) {
      const int bb = q * 4 + rr;
      out[((size_t)bb * 1024 + n) * 64 + o] = acc[tt][rr] + bv;
    }
  }
}

// ---------------------------------------------------------------------------
extern "C" void kernel_launch(void* const* d_in, const int* in_sizes, int n_in,
                              void* d_out, int out_size, void* d_ws,
                              size_t ws_size, hipStream_t stream) {
  const float* x   = (const float*)d_in[0];   // [16,1024,64]
  const float* adj = (const float*)d_in[1];   // [2,16,1024,1024]
  const float* emb = (const float*)d_in[2];   // [1024,10]
  const float* wp  = (const float*)d_in[3];   // [10,5,64,64]
  const float* bp  = (const float*)d_in[4];   // [10,64]
  float* out = (float*)d_out;                 // [16,1024,64]

  char* ws = (char*)d_ws;
  unsigned short* XT0  = (unsigned short*)(ws);                      // 2 MB
  unsigned short* XT1  = (unsigned short*)(ws + ((size_t)2 << 20));  // 4 MB
  unsigned short* X1b  = (unsigned short*)(ws + ((size_t)6 << 20));  // 4 MB
  unsigned short* X2b  = (unsigned short*)(ws + ((size_t)10 << 20)); // 4 MB
  unsigned short* wpTb = (unsigned short*)(ws + ((size_t)14 << 20)); // 0.41 MB

  prep<<<dim3(306), dim3(256), 0, stream>>>(x, wp, XT0, wpTb);
  hop1_kernel<<<dim3(16, 32), dim3(256), 0, stream>>>(adj, XT0, X1b, XT1);
  hop2_kernel<<<dim3(16, 32), dim3(256), 0, stream>>>(adj, XT1, X2b);
  final_kernel<<<dim3(512), dim3(256), 0, stream>>>(x, X1b, X2b, wpTb, emb,
                                                    bp, out);
}

// Round 2
// 290.579 us; speedup vs baseline: 1.0011x; 1.0011x over previous
//
#include <hip/hip_runtime.h>
#include <stdint.h>

// ---------------------------------------------------------------------------
// PDG2Seq_GCN: B=16, N=1024, C=O=64, D=10, CHEB_K=2 (K=5 stacked terms)
// Round 8: revert hops to bf16 adjb (R6 structure, proven faster than fp32
// staging), but replace the per-stage __syncthreads (vmcnt(0) drain) with the
// counted-vmcnt pipeline: 3-deep LDS buffers, raw s_barrier, vmcnt(4) per
// stage -> 2-stage prefetch depth, loads stay in flight across barriers.
// Keep R7's orthogonal wins: no WT materialization (final regenerates weights
// from L2-resident wpTb), bf16 X0b/X1b/X2b intermediates, cvt+prep fused.
// Launches: cvtprep, hop1, hop2, final (4 kernels).
// ---------------------------------------------------------------------------

typedef __attribute__((ext_vector_type(4))) float f32x4;
typedef __attribute__((ext_vector_type(2))) float f32x2;
typedef __attribute__((ext_vector_type(8))) short s16x8;
typedef __attribute__((ext_vector_type(8))) __bf16 bf16x8;

__device__ __forceinline__ unsigned short f2bf(float f) {
  union { float f; uint32_t u; } v; v.f = f;
  uint32_t r = v.u + 0x7FFFu + ((v.u >> 16) & 1u);   // RNE
  return (unsigned short)(r >> 16);
}
__device__ __forceinline__ uint32_t pack2(float a, float b) {
  return (uint32_t)f2bf(a) | ((uint32_t)f2bf(b) << 16);
}

union FragU { s16x8 s; bf16x8 b; uint32_t u[4]; };

__device__ __forceinline__ void async_cp16(const void* g, void* l) {
  __builtin_amdgcn_global_load_lds(
      (const __attribute__((address_space(1))) void*)g,
      (__attribute__((address_space(3))) void*)l, 16, 0, 0);
}

// ---------------------------------------------------------------------------
// K0 cvtprep: blocks 0..8191   : adj f32 -> adjb bf16 (grid-stride, 2 iters)
//             blocks 8192..8447: transpose x -> XT0 bf16 [b][c][n]
//                                + node-major X0b bf16 [b][n][c]
//             blocks 8448..8497: transpose wp -> wpTb bf16 [d][o][ki]
// ---------------------------------------------------------------------------
__global__ __launch_bounds__(256) void cvtprep(
    const float* __restrict__ adj, unsigned short* __restrict__ adjb,
    const float* __restrict__ x, const float* __restrict__ wp,
    unsigned short* __restrict__ XT0, unsigned short* __restrict__ X0b,
    unsigned short* __restrict__ wpTb) {
  __shared__ __align__(16) char smem[17160];
  const int tid = threadIdx.x;
  const int bid = blockIdx.x;

  if (bid < 8192) {
    const size_t stride = (size_t)8192 * 256 * 8;
    for (size_t p = ((size_t)bid * 256 + tid) * 8; p < 33554432u;
         p += stride) {
      f32x4 a = *(const f32x4*)(adj + p);
      f32x4 b = *(const f32x4*)(adj + p + 4);
      union { s16x8 s; uint32_t u[4]; } o;
      o.u[0] = pack2(a[0], a[1]);
      o.u[1] = pack2(a[2], a[3]);
      o.u[2] = pack2(b[0], b[1]);
      o.u[3] = pack2(b[2], b[3]);
      *(s16x8*)(adjb + p) = o.s;
    }
    return;
  }

  const int pid = bid - 8192;
  if (pid < 256) {
    unsigned short (*tl)[72] = (unsigned short(*)[72])smem;
    const int b = pid >> 4, n0 = (pid & 15) * 64;
    {
      const int c4 = (tid & 15) * 4;
#pragma unroll
      for (int i = 0; i < 4; ++i) {
        const int row = (tid >> 4) + i * 16;
        f32x4 v =
            *(const f32x4*)(x + ((size_t)(b * 1024 + n0 + row)) * 64 + c4);
        const uint32_t w0 = pack2(v[0], v[1]);
        const uint32_t w1 = pack2(v[2], v[3]);
        *(uint32_t*)&tl[row][c4]     = w0;
        *(uint32_t*)&tl[row][c4 + 2] = w1;
        const uint64_t wq = (uint64_t)w0 | ((uint64_t)w1 << 32);
        *(uint64_t*)(X0b + ((size_t)(b * 1024 + n0 + row)) * 64 + c4) = wq;
      }
    }
    __syncthreads();
    {
      const int c = tid >> 2;
      const int nch = (tid & 3) * 16;
      s16x8 s0, s1;
#pragma unroll
      for (int j = 0; j < 8; ++j) {
        s0[j] = (short)tl[nch + j][c];
        s1[j] = (short)tl[nch + 8 + j][c];
      }
      unsigned short* p = XT0 + (size_t)(b * 64 + c) * 1024 + n0 + nch;
      *(s16x8*)p = s0;
      *(s16x8*)(p + 8) = s1;
    }
  } else {
    float (*tl)[65] = (float(*)[65])smem;
    const int jj = pid - 256;
    const int d = jj / 5, ki0 = (jj % 5) * 64;
    const float* src = wp + (size_t)d * 20480;
    {
      const int o4 = (tid & 15) * 4;
#pragma unroll
      for (int i = 0; i < 4; ++i) {
        const int row = (tid >> 4) + i * 16;
        f32x4 v = *(const f32x4*)(src + (size_t)(ki0 + row) * 64 + o4);
        tl[row][o4] = v[0]; tl[row][o4 + 1] = v[1];
        tl[row][o4 + 2] = v[2]; tl[row][o4 + 3] = v[3];
      }
    }
    __syncthreads();
    {
      const int o = tid >> 2;
      const int kch = (tid & 3) * 16;
      unsigned short* dst =
          wpTb + (size_t)d * 20480 + (size_t)o * 320 + ki0 + kch;
      s16x8 s0, s1;
#pragma unroll
      for (int j = 0; j < 8; ++j) {
        s0[j] = (short)f2bf(tl[kch + j][o]);
        s1[j] = (short)f2bf(tl[kch + 8 + j][o]);
      }
      *(s16x8*)dst = s0;
      *(s16x8*)(dst + 8) = s1;
    }
  }
}

// ---------------------------------------------------------------------------
// hop body: out[64 rows][64] = A[1024x1024]bf16 @ X[1024x64]bf16, MFMA.
// 3-deep LDS buffering (A 8KB + B 8KB per stage, 48 KB total), counted-vmcnt
// pipeline: per stage {vmcnt(4); s_barrier; issue(k+2); compute(k)} — the
// wait precedes the barrier so ALL waves' stage-k DMAs have landed before any
// wave reads the tile; 8 loads/wave stay in flight across barriers.
// Chunk-XOR swizzle on the GLOBAL source (linear LDS dest), swizzled reads.
// ---------------------------------------------------------------------------
__device__ __forceinline__ void hop_body(
    char* smem, const unsigned short* __restrict__ A,
    const unsigned short* __restrict__ XT, unsigned short* __restrict__ Xoutb,
    unsigned short* __restrict__ XTout, int write_xt, int rowbase) {
  const int tid = threadIdx.x;
  const int wave = tid >> 6, lane = tid & 63;
  const int l15 = lane & 15, q = lane >> 4;

  unsigned short* const Ast = (unsigned short*)smem;           // [3][64][64]
  unsigned short* const Bst = (unsigned short*)smem + 12288;   // [3][64][64]

  const int sub = lane >> 3;            // row-in-8
  const int ch = lane & 7;              // 8-short chunk
  const unsigned short* asrc[2];
  const unsigned short* bsrc[2];
  int ldso[2];
#pragma unroll
  for (int i = 0; i < 2; ++i) {
    const int r = wave * 16 + i * 8 + sub;
    asrc[i] = A + (size_t)(rowbase + r) * 1024 + (ch ^ (r & 7)) * 8;
    bsrc[i] = XT + (size_t)r * 1024 + (ch ^ (r & 7)) * 8;
    ldso[i] = (wave * 16 + i * 8) * 64;
  }

  f32x4 acc[4];
#pragma unroll
  for (int t = 0; t < 4; ++t) acc[t] = (f32x4){0.f, 0.f, 0.f, 0.f};

  auto issue = [&](int s, int k0) {
#pragma unroll
    for (int i = 0; i < 2; ++i) {
      async_cp16(asrc[i] + k0, Ast + s * 4096 + ldso[i]);
      async_cp16(bsrc[i] + k0, Bst + s * 4096 + ldso[i]);
    }
  };
  const int sw = l15 & 7;
  auto compute = [&](int s) {
    const unsigned short* Ab = Ast + s * 4096 + (wave * 16 + l15) * 64;
    const unsigned short* Bb = Bst + s * 4096 + l15 * 64;
#pragma unroll
    for (int h = 0; h < 2; ++h) {
      const int cko = ((h * 4 + q) ^ sw) * 8;
      FragU af;
      af.s = *(const s16x8*)(Ab + cko);
#pragma unroll
      for (int t = 0; t < 4; ++t) {
        FragU bf;
        bf.s = *(const s16x8*)(Bb + t * 1024 + cko);
        acc[t] = __builtin_amdgcn_mfma_f32_16x16x32_bf16(af.b, bf.b, acc[t],
                                                         0, 0, 0);
      }
    }
  };

  issue(0, 0);
  issue(1, 64);
#pragma unroll 1
  for (int kt = 0; kt < 15; ++kt) {
    asm volatile("s_waitcnt vmcnt(4)" ::: "memory");   // stage kt landed
    __builtin_amdgcn_sched_barrier(0);
    __builtin_amdgcn_s_barrier();                      // all waves' kt landed
    __builtin_amdgcn_sched_barrier(0);
    if (kt < 14) issue((kt + 2) % 3, (kt + 2) * 64);
    compute(kt % 3);
  }
  asm volatile("s_waitcnt vmcnt(0)" ::: "memory");
  __builtin_amdgcn_sched_barrier(0);
  __builtin_amdgcn_s_barrier();
  __builtin_amdgcn_sched_barrier(0);
  compute(0);                                          // kt = 15 -> buf 0

  // Epilogue: transpose via LDS (reuse stage memory)
  __syncthreads();
  float (*tile)[65] = (float(*)[65])smem;
#pragma unroll
  for (int t = 0; t < 4; ++t)
#pragma unroll
    for (int rr = 0; rr < 4; ++rr)
      tile[wave * 16 + q * 4 + rr][t * 16 + l15] = acc[t][rr];
  __syncthreads();

  {  // node-major bf16 [n][c] for final_kernel
    const int row = tid >> 2;
    const int cb = (tid & 3) * 16;
    unsigned short* __restrict__ outp =
        Xoutb + (size_t)(rowbase + row) * 64 + cb;
    s16x8 s0, s1;
#pragma unroll
    for (int j = 0; j < 8; ++j) {
      s0[j] = (short)f2bf(tile[row][cb + j]);
      s1[j] = (short)f2bf(tile[row][cb + 8 + j]);
    }
    *(s16x8*)outp = s0;
    *(s16x8*)(outp + 8) = s1;
  }
  if (write_xt) {  // c-major bf16 [c][n] for next hop
    const int c = tid >> 2;
    const int nch = (tid & 3) * 16;
    unsigned short* __restrict__ xtp = XTout + (size_t)c * 1024 + rowbase + nch;
    s16x8 s0, s1;
#pragma unroll
    for (int j = 0; j < 8; ++j) {
      s0[j] = (short)f2bf(tile[nch + j][c]);
      s1[j] = (short)f2bf(tile[nch + 8 + j][c]);
    }
    *(s16x8*)xtp = s0;
    *(s16x8*)(xtp + 8) = s1;
  }
}

// ---------------------------------------------------------------------------
// K2 hop1: reads bf16 adjb (LLC-resident after cvtprep).
// ---------------------------------------------------------------------------
__global__ __launch_bounds__(256, 2) void hop1_kernel(
    const unsigned short* __restrict__ adjb,
    const unsigned short* __restrict__ XT0, unsigned short* __restrict__ X1b,
    unsigned short* __restrict__ XT1) {
  __shared__ __align__(16) char smem[49152];
  const int bx = blockIdx.x, slice = blockIdx.y, b = slice & 15;
  hop_body(smem, adjb + (size_t)slice * 1048576, XT0 + (size_t)b * 65536,
           X1b + (size_t)slice * 65536, XT1 + (size_t)slice * 65536, 1,
           bx * 64);
}

// ---------------------------------------------------------------------------
// K3 hop2: reversed block order (LLC-hot adjb tail first).
// ---------------------------------------------------------------------------
__global__ __launch_bounds__(256, 2) void hop2_kernel(
    const unsigned short* __restrict__ adjb,
    const unsigned short* __restrict__ XT1, unsigned short* __restrict__ X2b) {
  __shared__ __align__(16) char smem[49152];
  const int bx = 15 - (int)blockIdx.x;
  const int slice = 31 - (int)blockIdx.y;
  hop_body(smem, adjb + (size_t)slice * 1048576, XT1 + (size_t)slice * 65536,
           X2b + (size_t)slice * 65536, (unsigned short*)0, 0, bx * 64);
}

// ---------------------------------------------------------------------------
// K4 final: out[b,n,o] = sum_d emb[n,d] * (xg[b,n,:320] @ WpT_d[320,64])
//           + sum_d emb[n,d] * bp[d,o]
// Weights regenerated on the fly from L2-resident wpTb (410 KB) — no WT.
// All xg sources are bf16 now (X0b/X1b/X2b), staging is pure u32 copies.
// 2 nodes/block, 2 waves per node (o halves). grid 512, block 256.
// ---------------------------------------------------------------------------
__global__ __launch_bounds__(256, 2) void final_kernel(
    const unsigned short* __restrict__ X0b,
    const unsigned short* __restrict__ X1b,
    const unsigned short* __restrict__ X2b,
    const unsigned short* __restrict__ wpTb, const float* __restrict__ emb,
    const float* __restrict__ bias_pool, float* __restrict__ out) {
  __shared__ unsigned short xg[2][16][328];
  const int tid = threadIdx.x;
  const int node_base = blockIdx.x * 2;

  for (int u = tid; u < 5120; u += 256) {       // units of 2 ki
    const int nd = u / 2560;
    int rem = u - nd * 2560;
    const int bb = rem / 160;
    const int kiu = rem - bb * 160;
    const int ki = kiu * 2;
    const int k = ki >> 6;
    const int c = ki & 63;
    const int nn = node_base + nd;
    const unsigned short* base =
        k == 0 ? X0b
        : k == 1 ? X1b
        : k == 2 ? X2b
        : k == 3 ? X1b + 1048576 : X2b + 1048576;
    const uint32_t w =
        *(const uint32_t*)(base + ((size_t)bb * 1024 + nn) * 64 + c);
    *(uint32_t*)&xg[nd][bb][ki] = w;
  }
  __syncthreads();

  const int wave = tid >> 6, lane = tid & 63;
  const int nd = wave >> 1, oh = wave & 1;
  const int l15 = lane & 15, q = lane >> 4;
  const int n = node_base + nd;

  // Hoist A-frags (xg rows, bf16) for the whole d-loop: 40 VGPRs.
  FragU af[10];
#pragma unroll
  for (int ks = 0; ks < 10; ++ks)
    af[ks].s = *(const s16x8*)&xg[nd][l15][ks * 32 + q * 8];

  f32x4 acc[2];
  acc[0] = (f32x4){0.f, 0.f, 0.f, 0.f};
  acc[1] = (f32x4){0.f, 0.f, 0.f, 0.f};

  // o = (oh*2+tt)*16 + l15 ; wpTb layout [d][o][ki]
  const unsigned short* wb0 = wpTb + (size_t)(oh * 32 + l15) * 320 + q * 8;
#pragma unroll 1
  for (int d = 0; d < 10; ++d) {
    const unsigned short* wd = wb0 + (size_t)d * 20480;
    f32x4 tmp[2];
    tmp[0] = (f32x4){0.f, 0.f, 0.f, 0.f};
    tmp[1] = (f32x4){0.f, 0.f, 0.f, 0.f};
#pragma unroll
    for (int ks = 0; ks < 10; ++ks) {
#pragma unroll
      for (int tt = 0; tt < 2; ++tt) {
        FragU bf;
        bf.s = *(const s16x8*)(wd + tt * 5120 + ks * 32);
        tmp[tt] = __builtin_amdgcn_mfma_f32_16x16x32_bf16(af[ks].b, bf.b,
                                                          tmp[tt], 0, 0, 0);
      }
    }
    const float e = emb[n * 10 + d];
#pragma unroll
    for (int tt = 0; tt < 2; ++tt)
#pragma unroll
      for (int rr = 0; rr < 4; ++rr)
        acc[tt][rr] += e * tmp[tt][rr];
  }

#pragma unroll
  for (int tt = 0; tt < 2; ++tt) {
    const int o = (oh * 2 + tt) * 16 + l15;
    float bv = 0.f;
#pragma unroll
    for (int d = 0; d < 10; ++d)
      bv += emb[n * 10 + d] * bias_pool[d * 64 + o];
#pragma unroll
    for (int rr = 0; rr < 4; ++rr) {
      const int bb = q * 4 + rr;
      out[((size_t)bb * 1024 + n) * 64 + o] = acc[tt][rr] + bv;
    }
  }
}

// ---------------------------------------------------------------------------
extern "C" void kernel_launch(void* const* d_in, const int* in_sizes, int n_in,
                              void* d_out, int out_size, void* d_ws,
                              size_t ws_size, hipStream_t stream) {
  const float* x   = (const float*)d_in[0];   // [16,1024,64]
  const float* adj = (const float*)d_in[1];   // [2,16,1024,1024]
  const float* emb = (const float*)d_in[2];   // [1024,10]
  const float* wp  = (const float*)d_in[3];   // [10,5,64,64]
  const float* bp  = (const float*)d_in[4];   // [10,64]
  float* out = (float*)d_out;                 // [16,1024,64]

  char* ws = (char*)d_ws;
  unsigned short* adjb = (unsigned short*)(ws);                      // 67 MB
  unsigned short* XT0  = (unsigned short*)(ws + ((size_t)68 << 20)); // 2 MB
  unsigned short* XT1  = (unsigned short*)(ws + ((size_t)70 << 20)); // 4 MB
  unsigned short* X0b  = (unsigned short*)(ws + ((size_t)74 << 20)); // 2 MB
  unsigned short* X1b  = (unsigned short*)(ws + ((size_t)76 << 20)); // 4 MB
  unsigned short* X2b  = (unsigned short*)(ws + ((size_t)80 << 20)); // 4 MB
  unsigned short* wpTb = (unsigned short*)(ws + ((size_t)84 << 20)); // 0.41 MB

  cvtprep<<<dim3(8498), dim3(256), 0, stream>>>(adj, adjb, x, wp, XT0, X0b,
                                                wpTb);
  hop1_kernel<<<dim3(16, 32), dim3(256), 0, stream>>>(adjb, XT0, X1b, XT1);
  hop2_kernel<<<dim3(16, 32), dim3(256), 0, stream>>>(adjb, XT1, X2b);
  final_kernel<<<dim3(512), dim3(256), 0, stream>>>(X0b, X1b, X2b, wpTb, emb,
                                                    bp, out);
}